// Round 2
// baseline (4290.208 us; speedup 1.0000x reference)
//
#include <hip/hip_runtime.h>
#include <math.h>

// ---- problem constants ----
constexpr int V   = 32000;
constexpr int D   = 512;
constexpr int PDIM= 64;     // P
constexpr int NH  = 8;      // heads
constexpr int NL  = 6;      // layers
constexpr int DHD = 64;     // D/H
constexpr int FFD = 1024;   // FF
constexpr int S   = 1024;
constexpr int BB  = 4;      // batch
constexpr int BS  = BB * S; // 4096 rows

__device__ __forceinline__ float softplusf(float z) {
    // jax.nn.softplus = max(x,0) + log1p(exp(-|x|))
    return fmaxf(z, 0.0f) + log1pf(expf(-fabsf(z)));
}

// ---------------- embedding gather ----------------
__global__ void k_embed(const int* __restrict__ x, const float* __restrict__ emb,
                        float* __restrict__ h) {
    int row = blockIdx.x;          // 0..BS-1
    int t = threadIdx.x;           // 128 threads -> 128 float4 = 512 floats
    int id = x[row];
    const float4* src = reinterpret_cast<const float4*>(emb + (size_t)id * D);
    float4* dst = reinterpret_cast<float4*>(h + (size_t)row * D);
    dst[t] = src[t];
}

// ---------------- pos preprocessing ----------------
__global__ void k_posprep(const float* __restrict__ pos, const float* __restrict__ curv,
                          float* __restrict__ pmod, float* __restrict__ sq) {
    int i = blockIdx.x;            // row
    int l = threadIdx.x;           // 64 lanes (one wave)
    float c = *curv;
    float p = pos[i * PDIM + l];
    float pm = p * (1.0f + c * sinf(p * 0.1f));
    pmod[i * PDIM + l] = pm;
    float s = pm * pm;
    for (int off = 32; off > 0; off >>= 1) s += __shfl_down(s, off);
    if (l == 0) sq[i] = s;
}

// ---------------- inv_d2 (S x S) ----------------
__global__ __launch_bounds__(256) void k_invd2(const float* __restrict__ pmod,
                                               const float* __restrict__ sq,
                                               float* __restrict__ invd2) {
    __shared__ float Pi[64][PDIM];
    __shared__ float Pj[64][PDIM];
    int i0 = blockIdx.y * 64, j0 = blockIdx.x * 64;
    int tid = threadIdx.x;
    for (int k = 0; k < 4; k++) {
        int f = tid + k * 256;             // float4 index 0..1023
        int r = f >> 4, c4 = (f & 15) * 4;
        *(float4*)&Pi[r][c4] = *(const float4*)&pmod[(size_t)(i0 + r) * PDIM + c4];
        *(float4*)&Pj[r][c4] = *(const float4*)&pmod[(size_t)(j0 + r) * PDIM + c4];
    }
    __syncthreads();
    int ty = tid >> 4, tx = tid & 15;
    float acc[4][4] = {};
    for (int k = 0; k < PDIM; k++) {
        float a[4], b[4];
        #pragma unroll
        for (int q = 0; q < 4; q++) a[q] = Pi[ty * 4 + q][k];
        #pragma unroll
        for (int q = 0; q < 4; q++) b[q] = Pj[tx * 4 + q][k];
        #pragma unroll
        for (int qi = 0; qi < 4; qi++)
            #pragma unroll
            for (int qj = 0; qj < 4; qj++) acc[qi][qj] += a[qi] * b[qj];
    }
    for (int qi = 0; qi < 4; qi++) {
        float si = sq[i0 + ty * 4 + qi];
        for (int qj = 0; qj < 4; qj++) {
            float d2 = si + sq[j0 + tx * 4 + qj] - 2.0f * acc[qi][qj];
            d2 = fmaxf(d2, 1e-6f);
            invd2[(size_t)(i0 + ty * 4 + qi) * S + j0 + tx * 4 + qj] = 1.0f / d2;
        }
    }
}

// ---------------- mass = softplus(h @ mass_w + mass_b) ----------------
__global__ void k_mass(const float* __restrict__ h, const float* __restrict__ mw,
                       const float* __restrict__ mb, float* __restrict__ m) {
    int row = blockIdx.x;
    int lane = threadIdx.x;  // 64 = one wave
    float acc[NH] = {};
    for (int k = lane; k < D; k += 64) {
        float hv = h[(size_t)row * D + k];
        const float* wr = mw + (size_t)k * NH;
        #pragma unroll
        for (int o = 0; o < NH; o++) acc[o] += hv * wr[o];
    }
    #pragma unroll
    for (int o = 0; o < NH; o++)
        for (int off = 32; off > 0; off >>= 1) acc[o] += __shfl_down(acc[o], off);
    if (lane == 0) {
        #pragma unroll
        for (int o = 0; o < NH; o++)
            m[(size_t)row * NH + o] = softplusf(acc[o] + mb[o]);
    }
}

// ---------------- attention row sums -> 1/rowsum ----------------
__global__ __launch_bounds__(256) void k_rowsum(const float* __restrict__ m,
                                                const float* __restrict__ invd2,
                                                const float* __restrict__ g_l,
                                                float* __restrict__ invrs) {
    int tid = threadIdx.x;
    int w = tid >> 6, lane = tid & 63;
    int ri = blockIdx.x * 4 + w;        // [0, B*NH*S)
    int b  = ri >> 13;                   // / (NH*S)
    int hh = (ri >> 10) & 7;
    int i  = ri & 1023;
    float g = g_l[hh];
    float gm = g * m[(size_t)((b << 10) + i) * NH + hh];
    const float* idrow = invd2 + (size_t)i * S;
    const float* mrow  = m + (size_t)(b << 10) * NH + hh;
    float sum = 0.0f;
    for (int j = lane; j < S; j += 64) {
        float F = gm * mrow[(size_t)j * NH] * idrow[j];
        sum += fminf(F, 50.0f);
    }
    for (int off = 32; off > 0; off >>= 1) sum += __shfl_down(sum, off);
    if (lane == 0) invrs[ri] = 1.0f / sum;
}

// ---------------- fused attn @ v ----------------
__global__ __launch_bounds__(256) void k_attnv(const float* __restrict__ m,
                                               const float* __restrict__ v,
                                               const float* __restrict__ invd2,
                                               const float* __restrict__ invrs,
                                               const float* __restrict__ g_l,
                                               float* __restrict__ o) {
    __shared__ float Vs[64][DHD];   // 16 KB
    __shared__ float Ps[64][65];    // padded
    int i0 = blockIdx.x * 64;
    int hh = blockIdx.y;
    int b  = blockIdx.z;
    int tid = threadIdx.x;
    int ty = tid >> 4, tx = tid & 15;
    float g = g_l[hh];
    float gmi[4], irs[4];
    #pragma unroll
    for (int q = 0; q < 4; q++) {
        int i = i0 + ty * 4 + q;
        gmi[q] = g * m[(size_t)((b << 10) + i) * NH + hh];
        irs[q] = invrs[((b * NH + hh) << 10) + i];
    }
    float acc[4][4] = {};
    for (int jt = 0; jt < S / 64; jt++) {
        int j0 = jt * 64;
        // load V tile
        #pragma unroll
        for (int k = 0; k < 4; k++) {
            int f = tid + k * 256;
            int r = f >> 4, c4 = (f & 15) * 4;
            *(float4*)&Vs[r][c4] =
                *(const float4*)&v[(size_t)((b << 10) + j0 + r) * D + hh * DHD + c4];
        }
        // compute P tile
        #pragma unroll
        for (int q = 0; q < 4; q++) {
            int i = i0 + ty * 4 + q;
            const float* idr = invd2 + (size_t)i * S + j0;
            #pragma unroll
            for (int c = 0; c < 4; c++) {
                int j = tx * 4 + c;
                float mj = m[(size_t)((b << 10) + j0 + j) * NH + hh];
                float F = fminf(gmi[q] * mj * idr[j], 50.0f);
                Ps[ty * 4 + q][j] = F * irs[q];
            }
        }
        __syncthreads();
        #pragma unroll
        for (int jj = 0; jj < 64; jj++) {
            float a[4], bb[4];
            #pragma unroll
            for (int q = 0; q < 4; q++) a[q] = Ps[ty * 4 + q][jj];
            *(float4*)bb = *(float4*)&Vs[jj][tx * 4];
            #pragma unroll
            for (int qi = 0; qi < 4; qi++)
                #pragma unroll
                for (int qd = 0; qd < 4; qd++) acc[qi][qd] += a[qi] * bb[qd];
        }
        __syncthreads();
    }
    #pragma unroll
    for (int q = 0; q < 4; q++) {
        int i = i0 + ty * 4 + q;
        *(float4*)&o[(size_t)((b << 10) + i) * D + hh * DHD + tx * 4] = *(float4*)acc[q];
    }
}

// ---------------- generic fp32 GEMM: C = act(A @ W + bias) ----------------
// A: M x K row-major, W: K x N row-major. Tiles 64x64, BK=16, 256 threads.
// Used for the small-N layer GEMMs (N=512/1024) where grid size matters.
template <int ACT>
__global__ __launch_bounds__(256) void k_gemm(const float* __restrict__ A,
                                              const float* __restrict__ W,
                                              const float* __restrict__ bias,
                                              float* __restrict__ C,
                                              int M, int N, int K) {
    __shared__ float As[16][64];
    __shared__ float Ws[16][64];
    int m0 = blockIdx.y * 64, n0 = blockIdx.x * 64;
    int tid = threadIdx.x;
    int ty = tid >> 4, tx = tid & 15;
    float acc[4][4] = {};
    for (int k0 = 0; k0 < K; k0 += 16) {
        {
            int r = tid >> 2, q = (tid & 3) * 4;
            float4 av = *(const float4*)&A[(size_t)(m0 + r) * K + k0 + q];
            As[q + 0][r] = av.x; As[q + 1][r] = av.y;
            As[q + 2][r] = av.z; As[q + 3][r] = av.w;
            int wr = tid >> 4, wc = (tid & 15) * 4;
            *(float4*)&Ws[wr][wc] = *(const float4*)&W[(size_t)(k0 + wr) * N + n0 + wc];
        }
        __syncthreads();
        #pragma unroll
        for (int kk = 0; kk < 16; kk++) {
            float a[4], b[4];
            *(float4*)a = *(float4*)&As[kk][ty * 4];
            *(float4*)b = *(float4*)&Ws[kk][tx * 4];
            #pragma unroll
            for (int qi = 0; qi < 4; qi++)
                #pragma unroll
                for (int qj = 0; qj < 4; qj++) acc[qi][qj] += a[qi] * b[qj];
        }
        __syncthreads();
    }
    for (int qi = 0; qi < 4; qi++) {
        int row = m0 + ty * 4 + qi;
        int col = n0 + tx * 4;
        float4 bv = *(const float4*)&bias[col];
        float z[4] = {acc[qi][0] + bv.x, acc[qi][1] + bv.y,
                      acc[qi][2] + bv.z, acc[qi][3] + bv.w};
        if (ACT == 1) {
            #pragma unroll
            for (int j = 0; j < 4; j++)
                z[j] = 0.5f * z[j] * (1.0f + erff(z[j] * 0.70710678118f));
        }
        *(float4*)&C[(size_t)row * N + col] = *(float4*)z;
    }
}

// ---------------- big-tile fp32 GEMM for the head: 128x128, 8x8 microtile ----
// 64 FMA per 4 ds_read_b128 per thread-k (vs 16 per 2 in k_gemm) -> VALU-bound.
__global__ __launch_bounds__(256) void k_gemm128(const float* __restrict__ A,
                                                 const float* __restrict__ W,
                                                 const float* __restrict__ bias,
                                                 float* __restrict__ C,
                                                 int M, int N, int K) {
    __shared__ float As[16][132];   // padded: transposed A-tile, conflict-free writes
    __shared__ float Ws[16][128];
    int m0 = blockIdx.y * 128, n0 = blockIdx.x * 128;
    int tid = threadIdx.x;
    int ty = tid >> 4, tx = tid & 15;     // 16x16 threads, 8x8 outputs each
    float acc[8][8] = {};
    int ar = tid >> 1;                    // A stage: row 0..127
    int ak = (tid & 1) * 8;               // k-offset 0 or 8
    int wr = tid >> 4;                    // W stage: k-row 0..15
    int wc = (tid & 15) * 8;              // col 0..120
    for (int k0 = 0; k0 < K; k0 += 16) {
        float4 a0 = *(const float4*)&A[(size_t)(m0 + ar) * K + k0 + ak];
        float4 a1 = *(const float4*)&A[(size_t)(m0 + ar) * K + k0 + ak + 4];
        As[ak + 0][ar] = a0.x; As[ak + 1][ar] = a0.y;
        As[ak + 2][ar] = a0.z; As[ak + 3][ar] = a0.w;
        As[ak + 4][ar] = a1.x; As[ak + 5][ar] = a1.y;
        As[ak + 6][ar] = a1.z; As[ak + 7][ar] = a1.w;
        *(float4*)&Ws[wr][wc]     = *(const float4*)&W[(size_t)(k0 + wr) * N + n0 + wc];
        *(float4*)&Ws[wr][wc + 4] = *(const float4*)&W[(size_t)(k0 + wr) * N + n0 + wc + 4];
        __syncthreads();
        #pragma unroll
        for (int kk = 0; kk < 16; kk++) {
            float a[8], b[8];
            *(float4*)&a[0] = *(float4*)&As[kk][ty * 8];
            *(float4*)&a[4] = *(float4*)&As[kk][ty * 8 + 4];
            *(float4*)&b[0] = *(float4*)&Ws[kk][tx * 8];
            *(float4*)&b[4] = *(float4*)&Ws[kk][tx * 8 + 4];
            #pragma unroll
            for (int qi = 0; qi < 8; qi++)
                #pragma unroll
                for (int qj = 0; qj < 8; qj++) acc[qi][qj] += a[qi] * b[qj];
        }
        __syncthreads();
    }
    float4 bv0 = *(const float4*)&bias[n0 + tx * 8];
    float4 bv1 = *(const float4*)&bias[n0 + tx * 8 + 4];
    const float bb[8] = {bv0.x, bv0.y, bv0.z, bv0.w, bv1.x, bv1.y, bv1.z, bv1.w};
    for (int qi = 0; qi < 8; qi++) {
        int row = m0 + ty * 8 + qi;
        float z[8];
        #pragma unroll
        for (int j = 0; j < 8; j++) z[j] = acc[qi][j] + bb[j];
        *(float4*)&C[(size_t)row * N + n0 + tx * 8]     = *(float4*)&z[0];
        *(float4*)&C[(size_t)row * N + n0 + tx * 8 + 4] = *(float4*)&z[4];
    }
}

// ---------------- LayerNorm: out = LN(xin (+ res)) * s + b ----------------
__global__ __launch_bounds__(256) void k_ln(const float* __restrict__ xin,
                                            const float* __restrict__ res,
                                            const float* __restrict__ s,
                                            const float* __restrict__ bpar,
                                            float* __restrict__ out) {
    __shared__ float red[4];
    int row = blockIdx.x;
    int tid = threadIdx.x;   // 256 threads, 2 elems each (D=512)
    float v0 = xin[(size_t)row * D + tid];
    float v1 = xin[(size_t)row * D + tid + 256];
    if (res) {
        v0 += res[(size_t)row * D + tid];
        v1 += res[(size_t)row * D + tid + 256];
    }
    float sum = v0 + v1;
    for (int off = 32; off > 0; off >>= 1) sum += __shfl_down(sum, off);
    if ((tid & 63) == 0) red[tid >> 6] = sum;
    __syncthreads();
    float mu = (red[0] + red[1] + red[2] + red[3]) * (1.0f / D);
    __syncthreads();
    float d0 = v0 - mu, d1 = v1 - mu;
    float vs = d0 * d0 + d1 * d1;
    for (int off = 32; off > 0; off >>= 1) vs += __shfl_down(vs, off);
    if ((tid & 63) == 0) red[tid >> 6] = vs;
    __syncthreads();
    float var = (red[0] + red[1] + red[2] + red[3]) * (1.0f / D);
    float rstd = rsqrtf(var + 1e-5f);
    out[(size_t)row * D + tid]       = d0 * rstd * s[tid] + bpar[tid];
    out[(size_t)row * D + tid + 256] = d1 * rstd * s[tid + 256] + bpar[tid + 256];
}

extern "C" void kernel_launch(void* const* d_in, const int* in_sizes, int n_in,
                              void* d_out, int out_size, void* d_ws, size_t ws_size,
                              hipStream_t stream) {
    const int*   x       = (const int*)  d_in[0];
    const float* emb     = (const float*)d_in[1];
    const float* pos     = (const float*)d_in[2];
    const float* curv    = (const float*)d_in[3];
    const float* g_heads = (const float*)d_in[4];
    const float* v_w     = (const float*)d_in[5];
    const float* v_b     = (const float*)d_in[6];
    const float* mass_w  = (const float*)d_in[7];
    const float* mass_b  = (const float*)d_in[8];
    const float* out_w   = (const float*)d_in[9];
    const float* out_b   = (const float*)d_in[10];
    const float* ffn_w1  = (const float*)d_in[11];
    const float* ffn_b1  = (const float*)d_in[12];
    const float* ffn_w2  = (const float*)d_in[13];
    const float* ffn_b2  = (const float*)d_in[14];
    const float* ln1_s   = (const float*)d_in[15];
    const float* ln1_b   = (const float*)d_in[16];
    const float* ln2_s   = (const float*)d_in[17];
    const float* ln2_b   = (const float*)d_in[18];
    const float* fin_s   = (const float*)d_in[19];
    const float* fin_b   = (const float*)d_in[20];
    const float* head_w  = (const float*)d_in[21];
    const float* head_b  = (const float*)d_in[22];

    float* ws    = (float*)d_ws;
    float* h     = ws;                       // BS*D
    float* vbuf  = h    + (size_t)BS * D;    // BS*D
    float* obuf  = vbuf + (size_t)BS * D;    // BS*D
    float* fbuf  = obuf + (size_t)BS * D;    // BS*FF
    float* invd2 = fbuf + (size_t)BS * FFD;  // S*S
    float* pmod  = invd2 + (size_t)S * S;    // S*P
    float* sqv   = pmod + (size_t)S * PDIM;  // S
    float* mbuf  = sqv + S;                  // BS*NH
    float* invrs = mbuf + (size_t)BS * NH;   // B*NH*S

    k_embed<<<BS, 128, 0, stream>>>(x, emb, h);
    k_posprep<<<S, 64, 0, stream>>>(pos, curv, pmod, sqv);
    k_invd2<<<dim3(S / 64, S / 64), 256, 0, stream>>>(pmod, sqv, invd2);

    for (int l = 0; l < NL; l++) {
        const float* g_l = g_heads + l * NH;
        k_mass<<<BS, 64, 0, stream>>>(h, mass_w + (size_t)l * D * NH, mass_b + l * NH, mbuf);
        k_gemm<0><<<dim3(D / 64, BS / 64), 256, 0, stream>>>(
            h, v_w + (size_t)l * D * D, v_b + (size_t)l * D, vbuf, BS, D, D);
        k_rowsum<<<BB * NH * S / 4, 256, 0, stream>>>(mbuf, invd2, g_l, invrs);
        k_attnv<<<dim3(S / 64, NH, BB), 256, 0, stream>>>(mbuf, vbuf, invd2, invrs, g_l, obuf);
        k_gemm<0><<<dim3(D / 64, BS / 64), 256, 0, stream>>>(
            obuf, out_w + (size_t)l * D * D, out_b + (size_t)l * D, vbuf, BS, D, D);
        k_ln<<<BS, 256, 0, stream>>>(h, vbuf, ln1_s + (size_t)l * D, ln1_b + (size_t)l * D, h);
        k_gemm<1><<<dim3(FFD / 64, BS / 64), 256, 0, stream>>>(
            h, ffn_w1 + (size_t)l * D * FFD, ffn_b1 + (size_t)l * FFD, fbuf, BS, FFD, D);
        k_gemm<0><<<dim3(D / 64, BS / 64), 256, 0, stream>>>(
            fbuf, ffn_w2 + (size_t)l * FFD * D, ffn_b2 + (size_t)l * D, vbuf, BS, D, FFD);
        k_ln<<<BS, 256, 0, stream>>>(h, vbuf, ln2_s + (size_t)l * D, ln2_b + (size_t)l * D, h);
    }
    k_ln<<<BS, 256, 0, stream>>>(h, nullptr, fin_s, fin_b, obuf);
    k_gemm128<<<dim3(V / 128, BS / 128), 256, 0, stream>>>(
        obuf, head_w, head_b, (float*)d_out, BS, V, D);
}